// Round 9
// baseline (346.772 us; speedup 1.0000x reference)
//
#include <hip/hip_runtime.h>
#include <hip/hip_bf16.h>

// pooled[s] = sum_k ( S[s,k,:] @ W[k] ) + sum_k count[s,k]*b[k]
// S[s,k,:] = sum of atom rows in segment s with degree k.
//
// V8 = V7 with the divergent-shfl bug fixed (V7 failed absmax 43.75):
//   ds_bpermute under divergent exec read inactive lanes' registers when
//   n % 16 == 15 (deep loop) or in the per-lane tail guard. Fix: deep
//   loop bound is wave-uniform (m+16<=n, j=m+rpar inside); tail shuffles
//   run FULL-WAVE (indices clamped), only the loads are lane-predicated.
// phaseA concept (unchanged from V7):
//   - slot-vector prefetch: CAP==64==wave, sl[lane] = ONE coalesced 256B
//     load of the whole slot list, issued concurrently with cnt[bin];
//     row indices via __shfl -> no slot-refetch round-trips.
//   - 8-deep batched row loads -> bins with n<=15 (~92%) take one wait.
//   memset       : zero cnt (B*K u32, 180 KB)
//   k_fill_wconv : bucket-fill slots[key*CAP+p]=i; last K blocks W->bf16^T
//   k_phaseA     : one WAVE per (s,k) bin (above)
//   k_phaseB     : MFMA GEMM out = S @ Wb + (cnt . bias), plain stores
//
// Accounting (rounds 0/2/4/5/7): dur_us carries ~238us of harness poison
// fills; our pipeline ~108us of which phaseA ~90 (cold; 28 warm/L3 ->
// latency-bound). V4 (+28us redundant loads), V5 (2x, TLP halved),
// V6 tail-batch (neutral), V7 (divergent-shfl, WRONG) all archived.

#define CAP 64   // max atoms per (segment,degree) bin; == wavefront size

typedef short bf16x8 __attribute__((ext_vector_type(8)));
typedef float f32x4  __attribute__((ext_vector_type(4)));

__device__ __forceinline__ unsigned short f2bf(float f) {
    unsigned int u = __builtin_bit_cast(unsigned int, f);
    u += 0x7fffu + ((u >> 16) & 1u);
    return (unsigned short)(u >> 16);
}

__device__ __forceinline__ int deg_of(int i, const int* __restrict__ ds, int K) {
    int k = 0, end = 0;
    for (int kk = 0; kk < K; ++kk) { end += ds[2 * kk + 1]; k += (i >= end) ? 1 : 0; }
    return k;
}

// blocks [0,nb): bucket fill.  blocks [nb,nb+K): W[k][f][c] f32 -> Wb[k][c][f] bf16.
__global__ __launch_bounds__(256) void k_fill_wconv(
    const int* __restrict__ mem, const int* __restrict__ ds,
    const float* __restrict__ W,
    unsigned* __restrict__ cnt, unsigned* __restrict__ slots,
    unsigned short* __restrict__ Wb, int N, int K, int nb)
{
    int bx = blockIdx.x;
    if (bx >= nb) {
        __shared__ unsigned short t[128 * 130];
        int k = bx - nb;
        const float* Wk = W + (size_t)k * 16384;
        unsigned short* Wbk = Wb + (size_t)k * 16384;
        for (int e = threadIdx.x; e < 16384; e += 256) {
            int f = e >> 7, c = e & 127;
            t[f * 130 + c] = f2bf(Wk[e]);
        }
        __syncthreads();
        for (int e = threadIdx.x; e < 16384; e += 256) {
            int c = e >> 7, f = e & 127;
            Wbk[e] = t[f * 130 + c];
        }
        return;
    }
    int i = bx * 256 + threadIdx.x;
    if (i >= N) return;
    int key = mem[i] * K + deg_of(i, ds, K);
    unsigned p = atomicAdd(&cnt[key], 1u);
    if (p < CAP) slots[(size_t)key * CAP + p] = (unsigned)i;
}

__device__ __forceinline__ float4 f4add(float4 a, float4 b) {
    return make_float4(a.x + b.x, a.y + b.y, a.z + b.z, a.w + b.w);
}

// One WAVE per bin. Lanes: rpar = lane>>5 (row parity), f4 = lane&31
// (float4 within the 128-float row). Each row read = one contiguous 512 B.
// Chain: {cnt[bin] || sl[lane]} -> full-wave shfl row indices -> batches.
__global__ __launch_bounds__(256) void k_phaseA(
    const float* __restrict__ atoms,
    const unsigned* __restrict__ cnt,
    const unsigned* __restrict__ slots,
    unsigned short* __restrict__ S, int KB)
{
    int bin = blockIdx.x * 4 + (threadIdx.x >> 6);
    if (bin >= KB) return;
    int lane = threadIdx.x & 63;
    int rpar = lane >> 5;
    int f4   = lane & 31;
    const unsigned* sl = slots + (size_t)bin * CAP;

    // Two INDEPENDENT loads, issued back-to-back (one wait covers both):
    int n = (int)cnt[bin];          // bin row count (wave-uniform)
    unsigned slv = sl[lane];        // whole 64-slot list, 1 coalesced 256B
    if (n > CAP) n = CAP;

    const float4 z4 = make_float4(0.f, 0.f, 0.f, 0.f);
    float4 A0 = z4, A1 = z4;

    // Deep loop (n >= 16): WAVE-UNIFORM bound (n uniform) -> both
    // parities iterate in lockstep, shuffles see full exec. Row indices
    // j..j+14 <= m+15 <= n-1 are all valid.
    int m = 0;
    for (; m + 16 <= n; m += 16) {
        int j = m + rpar;
        unsigned r0 = __shfl(slv, j,      64);
        unsigned r1 = __shfl(slv, j + 2,  64);
        unsigned r2 = __shfl(slv, j + 4,  64);
        unsigned r3 = __shfl(slv, j + 6,  64);
        unsigned r4 = __shfl(slv, j + 8,  64);
        unsigned r5 = __shfl(slv, j + 10, 64);
        unsigned r6 = __shfl(slv, j + 12, 64);
        unsigned r7 = __shfl(slv, j + 14, 64);
        float4 v0 = *reinterpret_cast<const float4*>(atoms + (size_t)r0 * 128 + f4 * 4);
        float4 v1 = *reinterpret_cast<const float4*>(atoms + (size_t)r1 * 128 + f4 * 4);
        float4 v2 = *reinterpret_cast<const float4*>(atoms + (size_t)r2 * 128 + f4 * 4);
        float4 v3 = *reinterpret_cast<const float4*>(atoms + (size_t)r3 * 128 + f4 * 4);
        float4 v4 = *reinterpret_cast<const float4*>(atoms + (size_t)r4 * 128 + f4 * 4);
        float4 v5 = *reinterpret_cast<const float4*>(atoms + (size_t)r5 * 128 + f4 * 4);
        float4 v6 = *reinterpret_cast<const float4*>(atoms + (size_t)r6 * 128 + f4 * 4);
        float4 v7 = *reinterpret_cast<const float4*>(atoms + (size_t)r7 * 128 + f4 * 4);
        A0 = f4add(A0, f4add(f4add(v0, v1), f4add(v2, v3)));
        A1 = f4add(A1, f4add(f4add(v4, v5), f4add(v6, v7)));
    }

    // Tail (<=15 rows): guard is WAVE-UNIFORM (m,n uniform). All shuffles
    // execute full-wave with clamped indices; only the row LOADS are
    // lane-predicated (masked lanes fetch nothing, no duplicate traffic).
    // All issued loads sit under one waitcnt.
    if (m < n) {
        int j = m + rpar;                      // per-lane, but shfl is full-exec
        unsigned r0 = __shfl(slv, (j      < 64) ? j      : 63, 64);
        unsigned r1 = __shfl(slv, (j + 2  < 64) ? j + 2  : 63, 64);
        unsigned r2 = __shfl(slv, (j + 4  < 64) ? j + 4  : 63, 64);
        unsigned r3 = __shfl(slv, (j + 6  < 64) ? j + 6  : 63, 64);
        unsigned r4 = __shfl(slv, (j + 8  < 64) ? j + 8  : 63, 64);
        unsigned r5 = __shfl(slv, (j + 10 < 64) ? j + 10 : 63, 64);
        unsigned r6 = __shfl(slv, (j + 12 < 64) ? j + 12 : 63, 64);
        unsigned r7 = __shfl(slv, (j + 14 < 64) ? j + 14 : 63, 64);
        float4 v0 = z4, v1 = z4, v2 = z4, v3 = z4;
        float4 v4 = z4, v5 = z4, v6 = z4, v7 = z4;
        if (j      < n) v0 = *reinterpret_cast<const float4*>(atoms + (size_t)r0 * 128 + f4 * 4);
        if (j + 2  < n) v1 = *reinterpret_cast<const float4*>(atoms + (size_t)r1 * 128 + f4 * 4);
        if (j + 4  < n) v2 = *reinterpret_cast<const float4*>(atoms + (size_t)r2 * 128 + f4 * 4);
        if (j + 6  < n) v3 = *reinterpret_cast<const float4*>(atoms + (size_t)r3 * 128 + f4 * 4);
        if (j + 8  < n) v4 = *reinterpret_cast<const float4*>(atoms + (size_t)r4 * 128 + f4 * 4);
        if (j + 10 < n) v5 = *reinterpret_cast<const float4*>(atoms + (size_t)r5 * 128 + f4 * 4);
        if (j + 12 < n) v6 = *reinterpret_cast<const float4*>(atoms + (size_t)r6 * 128 + f4 * 4);
        if (j + 14 < n) v7 = *reinterpret_cast<const float4*>(atoms + (size_t)r7 * 128 + f4 * 4);
        A0 = f4add(A0, f4add(f4add(v0, v1), f4add(v2, v3)));
        A1 = f4add(A1, f4add(f4add(v4, v5), f4add(v6, v7)));
    }

    float4 Sm = f4add(A0, A1);
    Sm.x += __shfl_xor(Sm.x, 32, 64);           // merge row parities
    Sm.y += __shfl_xor(Sm.y, 32, 64);
    Sm.z += __shfl_xor(Sm.z, 32, 64);
    Sm.w += __shfl_xor(Sm.w, 32, 64);
    if (rpar == 0) {
        unsigned lo = (unsigned)f2bf(Sm.x) | ((unsigned)f2bf(Sm.y) << 16);
        unsigned hi = (unsigned)f2bf(Sm.z) | ((unsigned)f2bf(Sm.w) << 16);
        *reinterpret_cast<uint2*>(S + (size_t)bin * 128 + f4 * 4) = make_uint2(lo, hi);
    }
}

// One wave per (16 segments x 32 cols); K-chain = K*128. Bias from cnt.
__global__ __launch_bounds__(64) void k_phaseB(
    const unsigned short* __restrict__ S,   // [B][K*128] bf16
    const unsigned short* __restrict__ Wb,  // [K][128][128] bf16 ([k][col][f])
    const unsigned* __restrict__ cnt,       // [B*K]
    const float* __restrict__ bias,         // [K][128]
    float* __restrict__ out,                // [B][128]
    int K)
{
    int bx   = blockIdx.x;
    int s0   = (bx >> 2) * 16;
    int c0   = (bx & 3) * 32;
    int lane = threadIdx.x;
    int quad = lane >> 4, cb = lane & 15;

    const int KD = K * 128;
    f32x4 acc0 = (f32x4){0.f, 0.f, 0.f, 0.f};
    f32x4 acc1 = (f32x4){0.f, 0.f, 0.f, 0.f};

    const unsigned short* Arow = S  + (size_t)(s0 + cb) * KD + quad * 8;
    const unsigned short* B0   = Wb + (size_t)(c0 + cb)      * 128 + quad * 8;
    const unsigned short* B1   = Wb + (size_t)(c0 + 16 + cb) * 128 + quad * 8;

    #pragma unroll 1
    for (int kk = 0; kk < K; ++kk) {
        #pragma unroll
        for (int k0 = 0; k0 < 128; k0 += 32) {
            bf16x8 a  = *reinterpret_cast<const bf16x8*>(Arow + kk * 128 + k0);
            bf16x8 b0 = *reinterpret_cast<const bf16x8*>(B0 + (size_t)kk * 16384 + k0);
            bf16x8 b1 = *reinterpret_cast<const bf16x8*>(B1 + (size_t)kk * 16384 + k0);
            acc0 = __builtin_amdgcn_mfma_f32_16x16x32_bf16(a, b0, acc0, 0, 0, 0);
            acc1 = __builtin_amdgcn_mfma_f32_16x16x32_bf16(a, b1, acc1, 0, 0, 0);
        }
    }
    #pragma unroll
    for (int reg = 0; reg < 4; ++reg) {
        int s = s0 + quad * 4 + reg;
        float b0s = 0.f, b1s = 0.f;
        for (int k = 0; k < K; ++k) {
            float c = (float)cnt[(size_t)s * K + k];   // true count (bias exact)
            b0s += c * bias[k * 128 + c0 + cb];
            b1s += c * bias[k * 128 + c0 + 16 + cb];
        }
        out[(size_t)s * 128 + c0 + cb]      = acc0[reg] + b0s;
        out[(size_t)s * 128 + c0 + 16 + cb] = acc1[reg] + b1s;
    }
}

// ---------------- fallback (fused atomic kernel) if ws too small ----------
#define TM 64
#define LDA 136
#define LDW 136
__global__ __launch_bounds__(256, 2) void degree_affine_pool(
    const float* __restrict__ atoms, const float* __restrict__ W,
    const float* __restrict__ bias, const int* __restrict__ deg_slice,
    const int* __restrict__ membership, float* __restrict__ out, int K)
{
    __shared__ unsigned short Alds[TM * LDA];
    __shared__ unsigned short Wlds[128 * LDW];
    const int bid = blockIdx.x, tid = threadIdx.x;
    int k = -1, tile = 0, acc_t = 0;
    for (int kk = 0; kk < K; ++kk) {
        int c = deg_slice[2 * kk + 1];
        int nt = (c + TM - 1) >> 6;
        if (k < 0 && bid < acc_t + nt) { k = kk; tile = bid - acc_t; }
        acc_t += nt;
    }
    if (k < 0) return;
    const int start = deg_slice[2 * k], cnt = deg_slice[2 * k + 1];
    const int row0 = start + tile * TM;
    const int rows_valid = min(TM, cnt - tile * TM);
    for (int e = tid; e < TM * 32; e += 256) {
        int r = e >> 5, f4 = e & 31;
        float4 v = make_float4(0.f, 0.f, 0.f, 0.f);
        if (r < rows_valid)
            v = *reinterpret_cast<const float4*>(atoms + (size_t)(row0 + r) * 128 + f4 * 4);
        unsigned lo = (unsigned)f2bf(v.x) | ((unsigned)f2bf(v.y) << 16);
        unsigned hi = (unsigned)f2bf(v.z) | ((unsigned)f2bf(v.w) << 16);
        *reinterpret_cast<uint2*>(&Alds[r * LDA + f4 * 4]) = make_uint2(lo, hi);
    }
    const float* Wk = W + (size_t)k * 16384;
    for (int e = tid; e < 8192; e += 256) {
        int c = e & 127, f2 = e >> 7;
        unsigned p = (unsigned)f2bf(Wk[(2 * f2) * 128 + c]) |
                     ((unsigned)f2bf(Wk[(2 * f2 + 1) * 128 + c]) << 16);
        *reinterpret_cast<unsigned*>(&Wlds[c * LDW + 2 * f2]) = p;
    }
    __syncthreads();
    const int wave = tid >> 6, lane = tid & 63, quad = lane >> 4, cb = lane & 15;
    f32x4 acc[8];
    #pragma unroll
    for (int ct = 0; ct < 8; ++ct) acc[ct] = (f32x4){0.f, 0.f, 0.f, 0.f};
    #pragma unroll
    for (int k0 = 0; k0 < 128; k0 += 32) {
        bf16x8 af = *reinterpret_cast<const bf16x8*>(&Alds[(wave * 16 + cb) * LDA + k0 + quad * 8]);
        #pragma unroll
        for (int ct = 0; ct < 8; ++ct) {
            bf16x8 bf = *reinterpret_cast<const bf16x8*>(&Wlds[(ct * 16 + cb) * LDW + k0 + quad * 8]);
            acc[ct] = __builtin_amdgcn_mfma_f32_16x16x32_bf16(af, bf, acc[ct], 0, 0, 0);
        }
    }
    int segs[4]; bool valid[4];
    #pragma unroll
    for (int reg = 0; reg < 4; ++reg) {
        int rl = wave * 16 + quad * 4 + reg;
        valid[reg] = (rl < rows_valid);
        segs[reg] = valid[reg] ? membership[row0 + rl] : 0;
    }
    const float* bk = bias + k * 128;
    #pragma unroll
    for (int ct = 0; ct < 8; ++ct) {
        int col = ct * 16 + cb;
        float bv = bk[col];
        #pragma unroll
        for (int reg = 0; reg < 4; ++reg)
            if (valid[reg])
                __hip_atomic_fetch_add(out + (size_t)segs[reg] * 128 + col,
                                       acc[ct][reg] + bv, __ATOMIC_RELAXED,
                                       __HIP_MEMORY_SCOPE_AGENT);
    }
}
// ---------------------------------------------------------------------------

static inline size_t aln(size_t x) { return (x + 255) & ~(size_t)255; }

extern "C" void kernel_launch(void* const* d_in, const int* in_sizes, int n_in,
                              void* d_out, int out_size, void* d_ws, size_t ws_size,
                              hipStream_t stream) {
    const float* atoms = (const float*)d_in[0];
    const float* W     = (const float*)d_in[1];
    const float* bias  = (const float*)d_in[2];
    const int*   deg   = (const int*)d_in[3];
    const int*   mem   = (const int*)d_in[4];
    float*       out   = (float*)d_out;

    const int K  = in_sizes[3] / 2;      // 11
    const int N  = in_sizes[0] / 128;    // 393216
    const int B  = out_size / 128;       // 4096
    const int KB = B * K;                // 45056 bins

    // workspace plan (~23.6 MB)
    size_t oWb   = 0;                       size_t sWb   = (size_t)K * 16384 * 2;
    size_t oCnt  = aln(oWb + sWb);          size_t sCnt  = (size_t)KB * 4;
    size_t oSlot = aln(oCnt + sCnt);        size_t sSlot = (size_t)KB * CAP * 4;
    size_t oS    = aln(oSlot + sSlot);      size_t sS    = (size_t)KB * 128 * 2;
    size_t total = oS + sS;

    if (ws_size < total || (B & 15) != 0) {
        (void)hipMemsetAsync(d_out, 0, (size_t)out_size * sizeof(float), stream);
        const int blocks = (N + TM - 1) / TM + K;
        degree_affine_pool<<<blocks, 256, 0, stream>>>(atoms, W, bias, deg, mem, out, K);
        return;
    }

    char* ws = (char*)d_ws;
    unsigned short* Wb    = (unsigned short*)(ws + oWb);
    unsigned*       cnt   = (unsigned*)(ws + oCnt);
    unsigned*       slots = (unsigned*)(ws + oSlot);
    unsigned short* S     = (unsigned short*)(ws + oS);

    (void)hipMemsetAsync(cnt, 0, sCnt, stream);

    const int nb = (N + 255) / 256;
    k_fill_wconv<<<nb + K, 256, 0, stream>>>(mem, deg, W, cnt, slots, Wb, N, K, nb);
    k_phaseA    <<<(KB + 3) / 4, 256, 0, stream>>>(atoms, cnt, slots, S, KB);
    k_phaseB    <<<(B / 16) * 4, 64, 0, stream>>>(S, Wb, cnt, bias, out, K);
}

// Round 10
// 339.558 us; speedup vs baseline: 1.0212x; 1.0212x over previous
//
#include <hip/hip_runtime.h>
#include <hip/hip_bf16.h>

// pooled[s] = sum_k ( S[s,k,:] @ W[k] ) + sum_k count[s,k]*b[k]
// S[s,k,:] = sum of atom rows in segment s with degree k.
//
// V9 = V8 (passing, neutral) + DEGREE-MAJOR bin keys: key = k*B + s.
// Mechanism: concurrently-resident phaseA waves now gather from ~2
// adjacent 18MB degree blocks (36MB sliding window) instead of all 11
// (201MB) -> DRAM row-buffer locality for the random 512B row reads.
// phaseB reads S/cnt through the transposed index (stride-only change;
// A-fragment coalescing actually improves: 256B vs 2816B row stride).
//   memset       : zero cnt (B*K u32, 180 KB)
//   k_fill_wconv : bucket-fill slots[key*CAP+p]=i; last K blocks W->bf16^T
//   k_phaseA     : one WAVE per bin; slot-vector prefetch (sl[lane], one
//                  coalesced 256B load || cnt[bin]); 8-deep batched rows,
//                  wave-uniform guards (V7's divergent-shfl bug fixed in V8)
//   k_phaseB     : MFMA GEMM out = S @ Wb + (cnt . bias), plain stores
//
// Accounting (rounds 0-9): dur_us carries ~238us harness poison fills;
// our pipeline ~108us of which phaseA ~90 (cold; 28 warm/L3). Archived:
// V4 (+28us redundant loads), V5 (2x, TLP halved), V6 tail (neutral),
// V7 (divergent shfl, WRONG), V8 slot-prefetch (neutral).

#define CAP 64   // max atoms per (segment,degree) bin; == wavefront size

typedef short bf16x8 __attribute__((ext_vector_type(8)));
typedef float f32x4  __attribute__((ext_vector_type(4)));

__device__ __forceinline__ unsigned short f2bf(float f) {
    unsigned int u = __builtin_bit_cast(unsigned int, f);
    u += 0x7fffu + ((u >> 16) & 1u);
    return (unsigned short)(u >> 16);
}

__device__ __forceinline__ int deg_of(int i, const int* __restrict__ ds, int K) {
    int k = 0, end = 0;
    for (int kk = 0; kk < K; ++kk) { end += ds[2 * kk + 1]; k += (i >= end) ? 1 : 0; }
    return k;
}

// blocks [0,nb): bucket fill (degree-major keys).
// blocks [nb,nb+K): W[k][f][c] f32 -> Wb[k][c][f] bf16.
__global__ __launch_bounds__(256) void k_fill_wconv(
    const int* __restrict__ mem, const int* __restrict__ ds,
    const float* __restrict__ W,
    unsigned* __restrict__ cnt, unsigned* __restrict__ slots,
    unsigned short* __restrict__ Wb, int N, int K, int nb, int B)
{
    int bx = blockIdx.x;
    if (bx >= nb) {
        __shared__ unsigned short t[128 * 130];
        int k = bx - nb;
        const float* Wk = W + (size_t)k * 16384;
        unsigned short* Wbk = Wb + (size_t)k * 16384;
        for (int e = threadIdx.x; e < 16384; e += 256) {
            int f = e >> 7, c = e & 127;
            t[f * 130 + c] = f2bf(Wk[e]);
        }
        __syncthreads();
        for (int e = threadIdx.x; e < 16384; e += 256) {
            int c = e >> 7, f = e & 127;
            Wbk[e] = t[f * 130 + c];
        }
        return;
    }
    int i = bx * 256 + threadIdx.x;
    if (i >= N) return;
    int key = deg_of(i, ds, K) * B + mem[i];   // DEGREE-MAJOR
    unsigned p = atomicAdd(&cnt[key], 1u);
    if (p < CAP) slots[(size_t)key * CAP + p] = (unsigned)i;
}

__device__ __forceinline__ float4 f4add(float4 a, float4 b) {
    return make_float4(a.x + b.x, a.y + b.y, a.z + b.z, a.w + b.w);
}

// One WAVE per bin. Lanes: rpar = lane>>5 (row parity), f4 = lane&31
// (float4 within the 128-float row). Each row read = one contiguous 512 B.
// Chain: {cnt[bin] || sl[lane]} -> full-wave shfl row indices -> batches.
__global__ __launch_bounds__(256) void k_phaseA(
    const float* __restrict__ atoms,
    const unsigned* __restrict__ cnt,
    const unsigned* __restrict__ slots,
    unsigned short* __restrict__ S, int KB)
{
    int bin = blockIdx.x * 4 + (threadIdx.x >> 6);
    if (bin >= KB) return;
    int lane = threadIdx.x & 63;
    int rpar = lane >> 5;
    int f4   = lane & 31;
    const unsigned* sl = slots + (size_t)bin * CAP;

    // Two INDEPENDENT loads, issued back-to-back (one wait covers both):
    int n = (int)cnt[bin];          // bin row count (wave-uniform)
    unsigned slv = sl[lane];        // whole 64-slot list, 1 coalesced 256B
    if (n > CAP) n = CAP;

    const float4 z4 = make_float4(0.f, 0.f, 0.f, 0.f);
    float4 A0 = z4, A1 = z4;

    // Deep loop (n >= 16): WAVE-UNIFORM bound -> both parities lockstep,
    // shuffles see full exec. Row indices j..j+14 <= n-1 all valid.
    int m = 0;
    for (; m + 16 <= n; m += 16) {
        int j = m + rpar;
        unsigned r0 = __shfl(slv, j,      64);
        unsigned r1 = __shfl(slv, j + 2,  64);
        unsigned r2 = __shfl(slv, j + 4,  64);
        unsigned r3 = __shfl(slv, j + 6,  64);
        unsigned r4 = __shfl(slv, j + 8,  64);
        unsigned r5 = __shfl(slv, j + 10, 64);
        unsigned r6 = __shfl(slv, j + 12, 64);
        unsigned r7 = __shfl(slv, j + 14, 64);
        float4 v0 = *reinterpret_cast<const float4*>(atoms + (size_t)r0 * 128 + f4 * 4);
        float4 v1 = *reinterpret_cast<const float4*>(atoms + (size_t)r1 * 128 + f4 * 4);
        float4 v2 = *reinterpret_cast<const float4*>(atoms + (size_t)r2 * 128 + f4 * 4);
        float4 v3 = *reinterpret_cast<const float4*>(atoms + (size_t)r3 * 128 + f4 * 4);
        float4 v4 = *reinterpret_cast<const float4*>(atoms + (size_t)r4 * 128 + f4 * 4);
        float4 v5 = *reinterpret_cast<const float4*>(atoms + (size_t)r5 * 128 + f4 * 4);
        float4 v6 = *reinterpret_cast<const float4*>(atoms + (size_t)r6 * 128 + f4 * 4);
        float4 v7 = *reinterpret_cast<const float4*>(atoms + (size_t)r7 * 128 + f4 * 4);
        A0 = f4add(A0, f4add(f4add(v0, v1), f4add(v2, v3)));
        A1 = f4add(A1, f4add(f4add(v4, v5), f4add(v6, v7)));
    }

    // Tail (<=15 rows): WAVE-UNIFORM guard; shuffles full-wave (indices
    // clamped); only the row LOADS are lane-predicated.
    if (m < n) {
        int j = m + rpar;
        unsigned r0 = __shfl(slv, (j      < 64) ? j      : 63, 64);
        unsigned r1 = __shfl(slv, (j + 2  < 64) ? j + 2  : 63, 64);
        unsigned r2 = __shfl(slv, (j + 4  < 64) ? j + 4  : 63, 64);
        unsigned r3 = __shfl(slv, (j + 6  < 64) ? j + 6  : 63, 64);
        unsigned r4 = __shfl(slv, (j + 8  < 64) ? j + 8  : 63, 64);
        unsigned r5 = __shfl(slv, (j + 10 < 64) ? j + 10 : 63, 64);
        unsigned r6 = __shfl(slv, (j + 12 < 64) ? j + 12 : 63, 64);
        unsigned r7 = __shfl(slv, (j + 14 < 64) ? j + 14 : 63, 64);
        float4 v0 = z4, v1 = z4, v2 = z4, v3 = z4;
        float4 v4 = z4, v5 = z4, v6 = z4, v7 = z4;
        if (j      < n) v0 = *reinterpret_cast<const float4*>(atoms + (size_t)r0 * 128 + f4 * 4);
        if (j + 2  < n) v1 = *reinterpret_cast<const float4*>(atoms + (size_t)r1 * 128 + f4 * 4);
        if (j + 4  < n) v2 = *reinterpret_cast<const float4*>(atoms + (size_t)r2 * 128 + f4 * 4);
        if (j + 6  < n) v3 = *reinterpret_cast<const float4*>(atoms + (size_t)r3 * 128 + f4 * 4);
        if (j + 8  < n) v4 = *reinterpret_cast<const float4*>(atoms + (size_t)r4 * 128 + f4 * 4);
        if (j + 10 < n) v5 = *reinterpret_cast<const float4*>(atoms + (size_t)r5 * 128 + f4 * 4);
        if (j + 12 < n) v6 = *reinterpret_cast<const float4*>(atoms + (size_t)r6 * 128 + f4 * 4);
        if (j + 14 < n) v7 = *reinterpret_cast<const float4*>(atoms + (size_t)r7 * 128 + f4 * 4);
        A0 = f4add(A0, f4add(f4add(v0, v1), f4add(v2, v3)));
        A1 = f4add(A1, f4add(f4add(v4, v5), f4add(v6, v7)));
    }

    float4 Sm = f4add(A0, A1);
    Sm.x += __shfl_xor(Sm.x, 32, 64);           // merge row parities
    Sm.y += __shfl_xor(Sm.y, 32, 64);
    Sm.z += __shfl_xor(Sm.z, 32, 64);
    Sm.w += __shfl_xor(Sm.w, 32, 64);
    if (rpar == 0) {
        unsigned lo = (unsigned)f2bf(Sm.x) | ((unsigned)f2bf(Sm.y) << 16);
        unsigned hi = (unsigned)f2bf(Sm.z) | ((unsigned)f2bf(Sm.w) << 16);
        *reinterpret_cast<uint2*>(S + (size_t)bin * 128 + f4 * 4) = make_uint2(lo, hi);
    }
}

// One wave per (16 segments x 32 cols). S/cnt are DEGREE-MAJOR:
// S[(kk*B + s)*128 + f], cnt[k*B + s]. Bias from cnt.
__global__ __launch_bounds__(64) void k_phaseB(
    const unsigned short* __restrict__ S,   // [K][B][128] bf16 (degree-major)
    const unsigned short* __restrict__ Wb,  // [K][128][128] bf16 ([k][col][f])
    const unsigned* __restrict__ cnt,       // [K*B] (degree-major)
    const float* __restrict__ bias,         // [K][128]
    float* __restrict__ out,                // [B][128]
    int K, int B)
{
    int bx   = blockIdx.x;
    int s0   = (bx >> 2) * 16;
    int c0   = (bx & 3) * 32;
    int lane = threadIdx.x;
    int quad = lane >> 4, cb = lane & 15;

    f32x4 acc0 = (f32x4){0.f, 0.f, 0.f, 0.f};
    f32x4 acc1 = (f32x4){0.f, 0.f, 0.f, 0.f};

    const unsigned short* B0 = Wb + (size_t)(c0 + cb)      * 128 + quad * 8;
    const unsigned short* B1 = Wb + (size_t)(c0 + 16 + cb) * 128 + quad * 8;

    #pragma unroll 1
    for (int kk = 0; kk < K; ++kk) {
        const unsigned short* Ak = S + ((size_t)kk * B + s0 + cb) * 128 + quad * 8;
        #pragma unroll
        for (int k0 = 0; k0 < 128; k0 += 32) {
            bf16x8 a  = *reinterpret_cast<const bf16x8*>(Ak + k0);
            bf16x8 b0 = *reinterpret_cast<const bf16x8*>(B0 + (size_t)kk * 16384 + k0);
            bf16x8 b1 = *reinterpret_cast<const bf16x8*>(B1 + (size_t)kk * 16384 + k0);
            acc0 = __builtin_amdgcn_mfma_f32_16x16x32_bf16(a, b0, acc0, 0, 0, 0);
            acc1 = __builtin_amdgcn_mfma_f32_16x16x32_bf16(a, b1, acc1, 0, 0, 0);
        }
    }
    #pragma unroll
    for (int reg = 0; reg < 4; ++reg) {
        int s = s0 + quad * 4 + reg;
        float b0s = 0.f, b1s = 0.f;
        for (int k = 0; k < K; ++k) {
            float c = (float)cnt[(size_t)k * B + s];   // true count (bias exact)
            b0s += c * bias[k * 128 + c0 + cb];
            b1s += c * bias[k * 128 + c0 + 16 + cb];
        }
        out[(size_t)s * 128 + c0 + cb]      = acc0[reg] + b0s;
        out[(size_t)s * 128 + c0 + 16 + cb] = acc1[reg] + b1s;
    }
}

// ---------------- fallback (fused atomic kernel) if ws too small ----------
#define TM 64
#define LDA 136
#define LDW 136
__global__ __launch_bounds__(256, 2) void degree_affine_pool(
    const float* __restrict__ atoms, const float* __restrict__ W,
    const float* __restrict__ bias, const int* __restrict__ deg_slice,
    const int* __restrict__ membership, float* __restrict__ out, int K)
{
    __shared__ unsigned short Alds[TM * LDA];
    __shared__ unsigned short Wlds[128 * LDW];
    const int bid = blockIdx.x, tid = threadIdx.x;
    int k = -1, tile = 0, acc_t = 0;
    for (int kk = 0; kk < K; ++kk) {
        int c = deg_slice[2 * kk + 1];
        int nt = (c + TM - 1) >> 6;
        if (k < 0 && bid < acc_t + nt) { k = kk; tile = bid - acc_t; }
        acc_t += nt;
    }
    if (k < 0) return;
    const int start = deg_slice[2 * k], cnt = deg_slice[2 * k + 1];
    const int row0 = start + tile * TM;
    const int rows_valid = min(TM, cnt - tile * TM);
    for (int e = tid; e < TM * 32; e += 256) {
        int r = e >> 5, f4 = e & 31;
        float4 v = make_float4(0.f, 0.f, 0.f, 0.f);
        if (r < rows_valid)
            v = *reinterpret_cast<const float4*>(atoms + (size_t)(row0 + r) * 128 + f4 * 4);
        unsigned lo = (unsigned)f2bf(v.x) | ((unsigned)f2bf(v.y) << 16);
        unsigned hi = (unsigned)f2bf(v.z) | ((unsigned)f2bf(v.w) << 16);
        *reinterpret_cast<uint2*>(&Alds[r * LDA + f4 * 4]) = make_uint2(lo, hi);
    }
    const float* Wk = W + (size_t)k * 16384;
    for (int e = tid; e < 8192; e += 256) {
        int c = e & 127, f2 = e >> 7;
        unsigned p = (unsigned)f2bf(Wk[(2 * f2) * 128 + c]) |
                     ((unsigned)f2bf(Wk[(2 * f2 + 1) * 128 + c]) << 16);
        *reinterpret_cast<unsigned*>(&Wlds[c * LDW + 2 * f2]) = p;
    }
    __syncthreads();
    const int wave = tid >> 6, lane = tid & 63, quad = lane >> 4, cb = lane & 15;
    f32x4 acc[8];
    #pragma unroll
    for (int ct = 0; ct < 8; ++ct) acc[ct] = (f32x4){0.f, 0.f, 0.f, 0.f};
    #pragma unroll
    for (int k0 = 0; k0 < 128; k0 += 32) {
        bf16x8 af = *reinterpret_cast<const bf16x8*>(&Alds[(wave * 16 + cb) * LDA + k0 + quad * 8]);
        #pragma unroll
        for (int ct = 0; ct < 8; ++ct) {
            bf16x8 bf = *reinterpret_cast<const bf16x8*>(&Wlds[(ct * 16 + cb) * LDW + k0 + quad * 8]);
            acc[ct] = __builtin_amdgcn_mfma_f32_16x16x32_bf16(af, bf, acc[ct], 0, 0, 0);
        }
    }
    int segs[4]; bool valid[4];
    #pragma unroll
    for (int reg = 0; reg < 4; ++reg) {
        int rl = wave * 16 + quad * 4 + reg;
        valid[reg] = (rl < rows_valid);
        segs[reg] = valid[reg] ? membership[row0 + rl] : 0;
    }
    const float* bk = bias + k * 128;
    #pragma unroll
    for (int ct = 0; ct < 8; ++ct) {
        int col = ct * 16 + cb;
        float bv = bk[col];
        #pragma unroll
        for (int reg = 0; reg < 4; ++reg)
            if (valid[reg])
                __hip_atomic_fetch_add(out + (size_t)segs[reg] * 128 + col,
                                       acc[ct][reg] + bv, __ATOMIC_RELAXED,
                                       __HIP_MEMORY_SCOPE_AGENT);
    }
}
// ---------------------------------------------------------------------------

static inline size_t aln(size_t x) { return (x + 255) & ~(size_t)255; }

extern "C" void kernel_launch(void* const* d_in, const int* in_sizes, int n_in,
                              void* d_out, int out_size, void* d_ws, size_t ws_size,
                              hipStream_t stream) {
    const float* atoms = (const float*)d_in[0];
    const float* W     = (const float*)d_in[1];
    const float* bias  = (const float*)d_in[2];
    const int*   deg   = (const int*)d_in[3];
    const int*   mem   = (const int*)d_in[4];
    float*       out   = (float*)d_out;

    const int K  = in_sizes[3] / 2;      // 11
    const int N  = in_sizes[0] / 128;    // 393216
    const int B  = out_size / 128;       // 4096
    const int KB = B * K;                // 45056 bins

    // workspace plan (~23.6 MB)
    size_t oWb   = 0;                       size_t sWb   = (size_t)K * 16384 * 2;
    size_t oCnt  = aln(oWb + sWb);          size_t sCnt  = (size_t)KB * 4;
    size_t oSlot = aln(oCnt + sCnt);        size_t sSlot = (size_t)KB * CAP * 4;
    size_t oS    = aln(oSlot + sSlot);      size_t sS    = (size_t)KB * 128 * 2;
    size_t total = oS + sS;

    if (ws_size < total || (B & 15) != 0) {
        (void)hipMemsetAsync(d_out, 0, (size_t)out_size * sizeof(float), stream);
        const int blocks = (N + TM - 1) / TM + K;
        degree_affine_pool<<<blocks, 256, 0, stream>>>(atoms, W, bias, deg, mem, out, K);
        return;
    }

    char* ws = (char*)d_ws;
    unsigned short* Wb    = (unsigned short*)(ws + oWb);
    unsigned*       cnt   = (unsigned*)(ws + oCnt);
    unsigned*       slots = (unsigned*)(ws + oSlot);
    unsigned short* S     = (unsigned short*)(ws + oS);

    (void)hipMemsetAsync(cnt, 0, sCnt, stream);

    const int nb = (N + 255) / 256;
    k_fill_wconv<<<nb + K, 256, 0, stream>>>(mem, deg, W, cnt, slots, Wb, N, K, nb, B);
    k_phaseA    <<<(KB + 3) / 4, 256, 0, stream>>>(atoms, cnt, slots, S, KB);
    k_phaseB    <<<(B / 16) * 4, 64, 0, stream>>>(S, Wb, cnt, bias, out, K, B);
}